// Round 1
// 355.046 us; speedup vs baseline: 1.0062x; 1.0062x over previous
//
#include <hip/hip_runtime.h>
#include <hip/hip_bf16.h>

// S2Conv: x (512,64,121) f32, w (64,64,512) f32, Y (512,121) f32
// out (512,64,1771) f32.
// psi[e,g,i] = sum_n Y[n,i] w[e,g,n] / sqrt(512)
// out[b,g, OFF_l + u*d + m] = (1/8) sum_e psi[e,g,l^2+u] * x[b,e,l^2+m]
//
// Round 1 change: psi computed via MFMA GEMM (per-g block,
// C[i(121)][e(64)] = Y^T . w[:,g,:]^T, K=512) with hi/lo bf16 split for
// f32-equivalent precision, replacing the LDS-issue-bound VALU loop
// (was 5 ds_read_b32 per 4 FMAs). conv_kernel byte-identical to isolate delta.

#define OUTROW 1771
#define OUTB   113344  // 64*1771

typedef __attribute__((ext_vector_type(8))) short bf16x8;
typedef __attribute__((ext_vector_type(4))) float floatx4;

__device__ __constant__ int c_off[11] = {0,1,10,35,84,165,286,455,680,969,1330};
__device__ __constant__ signed char c_ltab[121] = {
  0,
  1,1,1,
  2,2,2,2,2,
  3,3,3,3,3,3,3,
  4,4,4,4,4,4,4,4,4,
  5,5,5,5,5,5,5,5,5,5,5,
  6,6,6,6,6,6,6,6,6,6,6,6,6,
  7,7,7,7,7,7,7,7,7,7,7,7,7,7,7,
  8,8,8,8,8,8,8,8,8,8,8,8,8,8,8,8,8,
  9,9,9,9,9,9,9,9,9,9,9,9,9,9,9,9,9,9,9,
  10,10,10,10,10,10,10,10,10,10,10,10,10,10,10,10,10,10,10,10,10
};

// ---------------------------------------------------------------------------
// Prep: blocks [0,64)   : psi via MFMA — one block per g.
//       blocks [64,576) : x_t — one block per b, float4-staged transpose.
// psi_t[64*l^2 + g*d + u][e] = scale * sum_n w[e,g,n]*Y[n,l^2+u]   (bf16)
// x_t [512*l^2 + b*d + m][e] = x[b,e,l^2+m]                        (bf16)
// ---------------------------------------------------------------------------
__global__ __launch_bounds__(256) void prep_kernel(
    const float* __restrict__ x, const float* __restrict__ w,
    const float* __restrict__ Y,
    __hip_bfloat16* __restrict__ psi_t, __hip_bfloat16* __restrict__ x_t)
{
  __shared__ float smem[8256];
  const int t = threadIdx.x;

  if (blockIdx.x < 64) {
    // ---- psi branch: MFMA GEMM C[i][e], rows i (121->128), cols e (64), K=512.
    // Fragment conventions copied from verified conv_kernel:
    //   a-frag: lane&15 -> row(i), (lane>>4)*8 -> K offset within K=32 step
    //   b-frag: lane&15 -> col(e), same K mapping
    //   D:      col = lane&15, row = (lane>>4)*4 + reg
    const int g    = blockIdx.x;
    const int wv   = t >> 6, lane = t & 63;
    const int ln15 = lane & 15, quad = lane >> 4;

    floatx4 acc[2][4] = {};   // [i-tile][e-tile], all statically indexed

    for (int n0 = 0; n0 < 512; n0 += 64) {
      __syncthreads();
      // stage Y chunk [64 n][121 i] f32 (31 KB), coalesced float4
      {
        const float4* src = (const float4*)(Y + n0*121);
        float4* dst = (float4*)smem;
        for (int idx = t; idx < 1936; idx += 256) dst[idx] = src[idx];
      }
      __syncthreads();

      #pragma unroll
      for (int ks = 0; ks < 2; ++ks) {            // two K=32 steps per chunk
        const int kb = ks*32 + quad*8;

        // A fragments (Y^T rows) from LDS, hi/lo split.
        // smem[(kb+j)*121 + irow]: 16 lanes consecutive irow -> <=2-way bank (free)
        bf16x8 ahi[2], alo[2];
        #pragma unroll
        for (int ti = 0; ti < 2; ++ti) {
          const int irow = (wv << 5) + (ti << 4) + ln15;   // i row, 0..127
          #pragma unroll
          for (int j = 0; j < 8; ++j) {
            float v = smem[(kb + j)*121 + irow];  // i>=121 reads in-bounds garbage, store-masked
            __hip_bfloat16 h = __float2bfloat16(v);
            float hf = __bfloat162float(h);
            __hip_bfloat16 lo = __float2bfloat16(v - hf);
            ahi[ti][j] = *(short*)&h;
            alo[ti][j] = *(short*)&lo;
          }
        }

        // B fragments (w rows, K-contiguous in memory) direct from global.
        bf16x8 bhi[4], blo[4];
        #pragma unroll
        for (int te = 0; te < 4; ++te) {
          const int e = (te << 4) + ln15;
          const float* wp = w + ((e << 6) + g)*512 + n0 + kb;  // 16B-aligned
          float4 wa = *(const float4*)wp;
          float4 wb = *(const float4*)(wp + 4);
          float v[8] = {wa.x, wa.y, wa.z, wa.w, wb.x, wb.y, wb.z, wb.w};
          #pragma unroll
          for (int j = 0; j < 8; ++j) {
            __hip_bfloat16 h = __float2bfloat16(v[j]);
            float hf = __bfloat162float(h);
            __hip_bfloat16 lo = __float2bfloat16(v[j] - hf);
            bhi[te][j] = *(short*)&h;
            blo[te][j] = *(short*)&lo;
          }
        }

        // 3-pass hi/lo MFMA: x*y ~= hi*hi + hi*lo + lo*hi  (lo*lo ~ 2^-18, dropped)
        #pragma unroll
        for (int ti = 0; ti < 2; ++ti) {
          #pragma unroll
          for (int te = 0; te < 4; ++te) {
            acc[ti][te] = __builtin_amdgcn_mfma_f32_16x16x32_bf16(ahi[ti], bhi[te], acc[ti][te], 0, 0, 0);
            acc[ti][te] = __builtin_amdgcn_mfma_f32_16x16x32_bf16(ahi[ti], blo[te], acc[ti][te], 0, 0, 0);
            acc[ti][te] = __builtin_amdgcn_mfma_f32_16x16x32_bf16(alo[ti], bhi[te], acc[ti][te], 0, 0, 0);
          }
        }
      }
    }

    // Epilogue: D row = (wv*32 + ti*16 + quad*4 + rr) = i, col = te*16+ln15 = e
    const float scale = 0.00552427172801990267f;  // 1/(8*sqrt(512))
    #pragma unroll
    for (int ti = 0; ti < 2; ++ti) {
      #pragma unroll
      for (int rr = 0; rr < 4; ++rr) {
        const int i = (wv << 5) + (ti << 4) + (quad << 2) + rr;
        if (i < 121) {
          int l = c_ltab[i];
          int d = 2*l + 1;
          int row = 64*l*l + g*d + (i - l*l);
          #pragma unroll
          for (int te = 0; te < 4; ++te) {
            __hip_bfloat16 hv = __float2bfloat16(acc[ti][te][rr] * scale);
            psi_t[row*64 + (te << 4) + ln15] = hv;   // 16 lanes -> 32B contiguous
          }
        }
      }
    }
  } else {
    // ---- x transpose branch: one block per b ----
    const int b = blockIdx.x - 64;
    {
      const float4* src = (const float4*)(x + b*7744);  // 7744 = 64*121, 16B-aligned
      float4* dst = (float4*)smem;                      // smem[e*121 + i]
      for (int idx = t; idx < 1936; idx += 256) dst[idx] = src[idx];
    }
    __syncthreads();
    const int wv = t >> 6, lane = t & 63;
    for (int ii = wv; ii < 121; ii += 4) {
      int l = c_ltab[ii];
      int d = 2*l + 1;
      int row = 512*l*l + b*d + (ii - l*l);
      // stride-121 LDS read: odd -> conflict-free; 128B fully-coalesced store
      x_t[row*64 + lane] = __float2bfloat16(smem[lane*121 + ii]);
    }
  }
}

// ---------------------------------------------------------------------------
// Main: per-l GEMM. Block tile: 64 p-rows x 256 q-cols, K=64.
// Wave w owns p-rows [p0+16w, +16), iterates 16 q-subtiles.
// Fragments loaded straight from global (K-contiguous bf16 rows), no LDS.
// (Unchanged this round to isolate the prep delta.)
// ---------------------------------------------------------------------------
__global__ __launch_bounds__(256) void conv_kernel(
    const __hip_bfloat16* __restrict__ psi_t,
    const __hip_bfloat16* __restrict__ x_t,
    float* __restrict__ out)
{
  const int bid = blockIdx.x;
  int l = 0;
  #pragma unroll
  for (int ll = 1; ll <= 10; ++ll)
    if (bid >= 2*c_off[ll]) l = ll;
  const int d = 2*l + 1;
  const int r = bid - 2*c_off[l];
  const int qtiles = 2*d;
  const int ptile = r / qtiles;
  const int qtile = r - ptile*qtiles;
  const int p0 = ptile*64, q0 = qtile*256;

  const int t = threadIdx.x;
  const int wv = t >> 6, lane = t & 63;
  const int ln15 = lane & 15, quad = lane >> 4;
  const int pw = p0 + wv*16;

  // A fragments: psi_t row = 64*l^2 + p, 8 bf16 at k-offset quad*8 (+32)
  const ushort* psiRow = (const ushort*)psi_t + (64*l*l + pw + ln15)*64 + quad*8;
  const bf16x8 af0 = *(const bf16x8*)(psiRow);
  const bf16x8 af1 = *(const bf16x8*)(psiRow + 32);

  // per-lane output row offsets for the 4 accumulator rows (p fixed per wave)
  int rowoff[4];
  #pragma unroll
  for (int rr = 0; rr < 4; ++rr) {
    int p  = pw + quad*4 + rr;
    int gg = p / d;
    int uu = p - gg*d;
    rowoff[rr] = gg*OUTROW + uu*d;
  }
  const int offl = c_off[l];
  const ushort* xbase = (const ushort*)x_t + 512*l*l*64 + quad*8;

  // incremental div/mod of q by d across qq steps (stepm < d -> one correction)
  const int stepd = 16 / d;
  const int stepm = 16 - stepd*d;
  int qlane = q0 + ln15;
  int bb = qlane / d;
  int mm = qlane - bb*d;

  #pragma unroll 4
  for (int qq = 0; qq < 16; ++qq) {
    const ushort* xr = xbase + (q0 + qq*16 + ln15)*64;
    bf16x8 bf0 = *(const bf16x8*)(xr);
    bf16x8 bf1 = *(const bf16x8*)(xr + 32);
    floatx4 acc = {0.f, 0.f, 0.f, 0.f};
    acc = __builtin_amdgcn_mfma_f32_16x16x32_bf16(af0, bf0, acc, 0, 0, 0);
    acc = __builtin_amdgcn_mfma_f32_16x16x32_bf16(af1, bf1, acc, 0, 0, 0);
    const int base = bb*OUTB + offl + mm;
    #pragma unroll
    for (int rr = 0; rr < 4; ++rr)
      out[base + rowoff[rr]] = acc[rr];
    bb += stepd; mm += stepm;
    if (mm >= d) { mm -= d; ++bb; }
  }
}

extern "C" void kernel_launch(void* const* d_in, const int* in_sizes, int n_in,
                              void* d_out, int out_size, void* d_ws, size_t ws_size,
                              hipStream_t stream) {
  const float* x = (const float*)d_in[0];   // 512*64*121
  const float* w = (const float*)d_in[1];   // 64*64*512
  const float* Y = (const float*)d_in[2];   // 512*121
  float* out = (float*)d_out;               // 512*64*1771

  __hip_bfloat16* psi_t = (__hip_bfloat16*)d_ws;                       // 7744*64 bf16 (<1MB)
  __hip_bfloat16* x_t   = (__hip_bfloat16*)((char*)d_ws + (1 << 20));  // 61952*64 bf16 (~7.9MB)

  prep_kernel<<<576, 256, 0, stream>>>(x, w, Y, psi_t, x_t);
  conv_kernel<<<3542, 256, 0, stream>>>(psi_t, x_t, out);
}